// Round 10
// baseline (149.985 us; speedup 1.0000x reference)
//
#include <hip/hip_runtime.h>
#include <hip/hip_bf16.h>

// InfoNCE loss, B=4096 D=768 N=8192, T=0.5, fp32 in, fp32 scalar out.
// R21: LDS-free main loop. R19/R20 established: (a) gemm is latency/
// LDS-pipe bound (MFMA<10%, VALU<25%, HBM<7% at all times), (b) resident
// waves dominate (R20: 140 VGPR -> 12 waves/CU -> 2x slower), (c) LDS
// pipe carries ~16us of the 31us (ds_read 11.7 + conflicts 1.9 + DMA 2.6).
// Key insight: fp4 32x32x64 fragment = 16B/lane at natural layout
// row*384 + w*64 + s*32 + half*16, and hn4 is 3 MB = L2-resident (XCD-
// swizzled), per-block tiles L1-cached across waves. So: load fragments
// DIRECTLY from global to registers (depth-1 rotating prefetch), zero
// LDS staging, zero swizzle, ZERO main-loop barriers. VGPR ~75 -> ~24
// waves/CU. Epilogue identical to R19 (DPP reduce, LDS partials, plain
// exactly-once part stores; single __syncthreads before merge).

#define B_SZ 4096
#define D_SZ 768
#define N_SZ 8192
#define ROWB 384  // fp4 bytes per row (768 * 0.5)
#define NSLAB 12  // 768 / 64 K-slabs of 32 B
constexpr float INV_T = 2.0f;  // 1/temperature

typedef float f32x16 __attribute__((ext_vector_type(16)));
typedef int i32x8 __attribute__((ext_vector_type(8)));
typedef int i32x4 __attribute__((ext_vector_type(4)));

// DPP half-wave (32-lane) sum on the VALU pipe: row_shr 1/2/4/8 then
// row_bcast:15 (row_mask 0xa) -> lanes 31 and 63 hold the two half sums.
// bound_ctrl=1: shifted-in lanes contribute 0.
__device__ inline float hsum32_dpp(float x) {
    float s = x, t;
    t = __int_as_float(__builtin_amdgcn_update_dpp(0, __float_as_int(s), 0x111, 0xf, 0xf, true)); s += t;
    t = __int_as_float(__builtin_amdgcn_update_dpp(0, __float_as_int(s), 0x112, 0xf, 0xf, true)); s += t;
    t = __int_as_float(__builtin_amdgcn_update_dpp(0, __float_as_int(s), 0x114, 0xf, 0xf, true)); s += t;
    t = __int_as_float(__builtin_amdgcn_update_dpp(0, __float_as_int(s), 0x118, 0xf, 0xf, true)); s += t;
    t = __int_as_float(__builtin_amdgcn_update_dpp(0, __float_as_int(s), 0x142, 0xa, 0xf, true)); s += t;
    return s;  // valid in lanes 31 and 63
}

// e2m1 encode of v (pre-scaled); levels 0,.5,1,1.5,2,3,4,6; round-to-nearest.
__device__ inline unsigned fp4_enc(float v) {
    float a = fabsf(v);
    unsigned c;
    if (a < 1.25f)      c = (a < 0.25f) ? 0u : (a < 0.75f) ? 1u : 2u;
    else if (a < 2.5f)  c = (a < 1.75f) ? 3u : 4u;
    else                c = (a < 3.5f) ? 5u : (a < 5.0f) ? 6u : 7u;
    return c | (v < 0.f ? 8u : 0u);
}

// ---- 1) fused prep: norms + positives + fp4 rows + out zeroing ----
// One wave per pair i. Lane l owns elements 12l..12l+11 (3 contiguous float4).
__global__ __launch_bounds__(256) void prep_k(const float* __restrict__ h1,
                                              const float* __restrict__ h2,
                                              unsigned char* __restrict__ hn4,
                                              float* __restrict__ pos,
                                              float* __restrict__ out) {
    if (blockIdx.x == 0 && threadIdx.x == 0) out[0] = 0.f;  // before finalize (stream order)
    const int i = blockIdx.x * 4 + (threadIdx.x >> 6);
    const int lane = threadIdx.x & 63;
    const float4* a4 = (const float4*)(h1 + (size_t)i * D_SZ);
    const float4* b4 = (const float4*)(h2 + (size_t)i * D_SZ);
    float4 av[3], bv[3];
    float sa = 0.f, sb = 0.f, dt = 0.f;
#pragma unroll
    for (int j = 0; j < 3; ++j) {
        av[j] = a4[lane * 3 + j];
        bv[j] = b4[lane * 3 + j];
        sa += av[j].x * av[j].x + av[j].y * av[j].y + av[j].z * av[j].z + av[j].w * av[j].w;
        sb += bv[j].x * bv[j].x + bv[j].y * bv[j].y + bv[j].z * bv[j].z + bv[j].w * bv[j].w;
        dt += av[j].x * bv[j].x + av[j].y * bv[j].y + av[j].z * bv[j].z + av[j].w * bv[j].w;
    }
#pragma unroll
    for (int m = 1; m < 64; m <<= 1) {
        sa += __shfl_xor(sa, m, 64);
        sb += __shfl_xor(sb, m, 64);
        dt += __shfl_xor(dt, m, 64);
    }
    const float n1 = fmaxf(sqrtf(sa), 1e-8f), n2 = fmaxf(sqrtf(sb), 1e-8f);
    const float i1 = 1.0f / n1, i2 = 1.0f / n2;
    const float s1 = i1 * 16.0f, s2 = i2 * 16.0f;  // fp4 stores v*16, scale 2^-4
    unsigned short* d1 = (unsigned short*)(hn4 + (size_t)i * ROWB);
    unsigned short* d2 = (unsigned short*)(hn4 + (size_t)(i + B_SZ) * ROWB);
#pragma unroll
    for (int j = 0; j < 3; ++j) {
        float va[4] = {av[j].x, av[j].y, av[j].z, av[j].w};
        float vb[4] = {bv[j].x, bv[j].y, bv[j].z, bv[j].w};
        unsigned u1 = 0, u2 = 0;
#pragma unroll
        for (int e = 0; e < 4; ++e) {
            u1 |= fp4_enc(va[e] * s1) << (4 * e);
            u2 |= fp4_enc(vb[e] * s2) << (4 * e);
        }
        d1[lane * 3 + j] = (unsigned short)u1;
        d2[lane * 3 + j] = (unsigned short)u2;
    }
    if (lane == 0) {
        float p = dt * i1 * i2 * INV_T;
        pos[i] = p;
        pos[i + B_SZ] = p;
    }
}

// ---- 2) symmetric fused sim-GEMM (MX-fp4, 32x32x64) + exp partial sums ----
// 128x128 tile, 8 waves (512 thr): wave w = m-strip (w&3)*32 x n-half
// (w>>2)*64, acc[2]=32 regs. Fragments loaded DIRECTLY from global
// (L2-resident 3MB table, L1 reuse across waves), 16B/lane/slab at
// row*384 + t*32 + half*16; depth-1 rotating prefetch; no LDS, no
// barriers in the main loop.
#define BM 128

__global__ __launch_bounds__(512) void gemm_reduce_k(const unsigned char* __restrict__ hn4,
                                                     float* __restrict__ part) {
    __shared__ float rowS[256];  // [nh=2][128]
    __shared__ float colS[512];  // [ms=4][128]
    // bijective XCD swizzle (2080 % 8 == 0): contiguous tri-indices per XCD
    const int b0 = blockIdx.x;
    const int b = (b0 & 7) * 260 + (b0 >> 3);
    // triangular index -> (ty, tx), ty <= tx
    int tx = (int)((sqrtf(8.0f * (float)b + 1.0f) - 1.0f) * 0.5f);
    while ((tx + 1) * (tx + 2) / 2 <= b) ++tx;
    while (tx * (tx + 1) / 2 > b) --tx;
    const int ty = b - tx * (tx + 1) / 2;
    const int rowBase = ty * BM;
    const int colBase = tx * BM;
    const bool diagBlk = (ty == tx);

    const int tid = threadIdx.x;
    const int wave = tid >> 6;   // 0..7
    const int lane = tid & 63;
    const int l32 = lane & 31;
    const int half = lane >> 5;
    const int ms = wave & 3;     // m-strip (32 rows)
    const int nh = wave >> 2;    // n-half (64 cols)

    f32x16 acc[2];
#pragma unroll
    for (int nt = 0; nt < 2; ++nt)
#pragma unroll
        for (int j = 0; j < 16; ++j) acc[nt][j] = 0.f;

    // per-lane fragment pointers (natural layout; 16B per slab each)
    const unsigned char* pa =
        hn4 + (size_t)(rowBase + ms * 32 + l32) * ROWB + half * 16;
    const unsigned char* pb0 =
        hn4 + (size_t)(colBase + nh * 64 + l32) * ROWB + half * 16;
    const unsigned char* pb1 = pb0 + 32 * ROWB;

    i32x4 ac = *(const i32x4*)pa;
    i32x4 b0c = *(const i32x4*)pb0;
    i32x4 b1c = *(const i32x4*)pb1;
    for (int t = 0; t < NSLAB; ++t) {
        i32x4 an, b0n, b1n;
        if (t + 1 < NSLAB) {  // depth-1 prefetch; flies under the 2 MFMAs
            const int o = (t + 1) * 32;
            an  = *(const i32x4*)(pa + o);
            b0n = *(const i32x4*)(pb0 + o);
            b1n = *(const i32x4*)(pb1 + o);
        }
        i32x8 a  = {ac[0], ac[1], ac[2], ac[3], 0, 0, 0, 0};
        i32x8 v0 = {b0c[0], b0c[1], b0c[2], b0c[3], 0, 0, 0, 0};
        i32x8 v1 = {b1c[0], b1c[1], b1c[2], b1c[3], 0, 0, 0, 0};
        // fmtA=fmtB=4 (fp4); scales 2^-3 (0x7C) x 2^-4 (0x7B):
        // (16a*16b)*2^-7 = 2ab = sim/T folded into the MFMA.
        acc[0] = __builtin_amdgcn_mfma_scale_f32_32x32x64_f8f6f4(
            a, v0, acc[0], 4, 4, 0, 0x7C7C7C7C, 0, 0x7B7B7B7B);
        acc[1] = __builtin_amdgcn_mfma_scale_f32_32x32x64_f8f6f4(
            a, v1, acc[1], 4, 4, 0, 0x7C7C7C7C, 0, 0x7B7B7B7B);
        ac = an; b0c = b0n; b1c = b1n;
    }

    // epilogue: 32x32 C/D layout col=l32, row=(j&3)+8*(j>>2)+4*half
    // (shape-determined, verified R5..R10). Row-reduce on the VALU pipe
    // (DPP), per-wave partials into disjoint LDS slots, then PLAIN
    // exactly-once stores to part (no atomics).
    float rs[16];
#pragma unroll
    for (int j = 0; j < 16; ++j) rs[j] = 0.f;
    float csum[2] = {0.f, 0.f};
#pragma unroll
    for (int nt = 0; nt < 2; ++nt) {
        const int col = colBase + nh * 64 + nt * 32 + l32;
#pragma unroll
        for (int j = 0; j < 16; ++j) {
            const int row = rowBase + ms * 32 + (j & 3) + 8 * (j >> 2) + 4 * half;
            float e = __expf(acc[nt][j]);  // acc already = sim/T
            e = (diagBlk && row == col) ? 0.f : e;
            rs[j] += e;
            csum[nt] += e;
        }
    }
#pragma unroll
    for (int j = 0; j < 16; ++j) rs[j] = hsum32_dpp(rs[j]);  // lanes 31/63 valid
    if (l32 == 31) {  // lanes 31 and 63 (half 0/1) hold different rows
#pragma unroll
        for (int j = 0; j < 16; ++j)
            rowS[nh * 128 + ms * 32 + (j & 3) + 8 * (j >> 2) + 4 * half] = rs[j];
    }
#pragma unroll
    for (int nt = 0; nt < 2; ++nt) {
        float c = csum[nt] + __shfl_xor(csum[nt], 32, 64);
        if (half == 0) colS[ms * 128 + nh * 64 + nt * 32 + l32] = c;
    }
    __syncthreads();
    // part[a][b][r]: a<b row-part of block (a,b); a>b col-part of (b,a);
    // a==b diag row-part. Every slot written exactly once -> no zero/atomic.
    if (tid < 128) {
        part[((size_t)ty * 64 + tx) * 128 + tid] = rowS[tid] + rowS[128 + tid];
    } else if (tid < 256 && !diagBlk) {
        const int c = tid - 128;
        part[((size_t)tx * 64 + ty) * 128 + c] =
            colS[c] + colS[128 + c] + colS[256 + c] + colS[384 + c];
    }
}

// ---- 3) loss: 64 blocks x 128 thr; row r of tile t: sum 64 partials,
// log - pos, block-reduce, 64 atomicAdds on out[0] (zeroed by prep). ----
__global__ __launch_bounds__(128) void finalize_k(const float* __restrict__ part,
                                                  const float* __restrict__ pos,
                                                  float* __restrict__ out) {
    __shared__ float red[2];
    const int t = blockIdx.x;
    const int r = threadIdx.x;
    const float* p = part + (size_t)t * 64 * 128 + r;
    float s = 0.f;
#pragma unroll 16
    for (int u = 0; u < 64; ++u) s += p[u * 128];
    const int i = t * 128 + r;
    float v = __logf(s) - pos[i];
#pragma unroll
    for (int m = 1; m < 64; m <<= 1) v += __shfl_xor(v, m, 64);
    if ((r & 63) == 0) red[r >> 6] = v;
    __syncthreads();
    if (r == 0) atomicAdd(out, (red[0] + red[1]) * (1.0f / (float)N_SZ));
}

extern "C" void kernel_launch(void* const* d_in, const int* in_sizes, int n_in,
                              void* d_out, int out_size, void* d_ws, size_t ws_size,
                              hipStream_t stream) {
    const float* h1 = (const float*)d_in[0];
    const float* h2 = (const float*)d_in[1];
    float* out = (float*)d_out;

    char* ws = (char*)d_ws;
    unsigned char* hn4 = (unsigned char*)ws;                     // N*384 = 3,145,728 B
    float* pos  = (float*)(ws + (size_t)N_SZ * ROWB);            // 32 KB
    float* part = (float*)(ws + (size_t)N_SZ * ROWB + 32768);    // 64*64*128*4 = 2 MB

    prep_k<<<B_SZ / 4, 256, 0, stream>>>(h1, h2, hn4, pos, out);
    const int nTiles = N_SZ / BM;                    // 64
    const int nBlocks = nTiles * (nTiles + 1) / 2;   // 2080
    gemm_reduce_k<<<nBlocks, 512, 0, stream>>>(hn4, part);
    finalize_k<<<64, 128, 0, stream>>>(part, pos, out);
}

// Round 11
// 112.524 us; speedup vs baseline: 1.3329x; 1.3329x over previous
//
#include <hip/hip_runtime.h>
#include <hip/hip_bf16.h>

// InfoNCE loss, B=4096 D=768 N=8192, T=0.5, fp32 in, fp32 scalar out.
// R22: R19 (best, 103.0us) + A-operand off the LDS pipe. R21 proved
// direct-global FRAGMENT loads are latency-naked when the whole operand
// stream depends on them (gemm 79us) -- but also that the VM path is
// idle (HBM 1.8%, L2 spare). So: B stays LDS-staged (DMA decouples
// latency); A goes direct-from-global with ONE-WINDOW-AHEAD register
// prefetch (issued with the B staging for w+1 -> ~full window in flight
// before use). Per window per wave: 4 ds_read (was 6) + 2 A global loads
// + 4 MFMA. ds_read/block 288->192 (-33%), staging DMA halved, LDS 16KB.
// B swizzle unchanged (write slot l&1 for row rb+(l>>1) holds chunk
// (l&1)^((l>>3)&1), matches read p=half^((l32>>2)&1)). VGPR ~70 < 128
// cap. Epilogue (DPP reduce, LDS partials, exactly-once part stores),
// prep, finalize byte-identical to R19.

#define B_SZ 4096
#define D_SZ 768
#define N_SZ 8192
#define ROWB 384  // fp4 bytes per row (768 * 0.5)
constexpr float INV_T = 2.0f;  // 1/temperature

typedef float f32x16 __attribute__((ext_vector_type(16)));
typedef int i32x8 __attribute__((ext_vector_type(8)));
typedef int i32x4 __attribute__((ext_vector_type(4)));
typedef __attribute__((address_space(1))) const unsigned int gu32;
typedef __attribute__((address_space(3))) unsigned int lu32;

__device__ inline void async16(const void* g, void* l) {
    // per-lane global addr, wave-uniform LDS base; lane i lands at base + i*16.
    __builtin_amdgcn_global_load_lds((gu32*)g, (lu32*)l, 16, 0, 0);
}

// DPP half-wave (32-lane) sum on the VALU pipe: row_shr 1/2/4/8 then
// row_bcast:15 (row_mask 0xa) -> lanes 31 and 63 hold the two half sums.
// bound_ctrl=1: shifted-in lanes contribute 0.
__device__ inline float hsum32_dpp(float x) {
    float s = x, t;
    t = __int_as_float(__builtin_amdgcn_update_dpp(0, __float_as_int(s), 0x111, 0xf, 0xf, true)); s += t;
    t = __int_as_float(__builtin_amdgcn_update_dpp(0, __float_as_int(s), 0x112, 0xf, 0xf, true)); s += t;
    t = __int_as_float(__builtin_amdgcn_update_dpp(0, __float_as_int(s), 0x114, 0xf, 0xf, true)); s += t;
    t = __int_as_float(__builtin_amdgcn_update_dpp(0, __float_as_int(s), 0x118, 0xf, 0xf, true)); s += t;
    t = __int_as_float(__builtin_amdgcn_update_dpp(0, __float_as_int(s), 0x142, 0xa, 0xf, true)); s += t;
    return s;  // valid in lanes 31 and 63
}

// e2m1 encode of v (pre-scaled); levels 0,.5,1,1.5,2,3,4,6; round-to-nearest.
__device__ inline unsigned fp4_enc(float v) {
    float a = fabsf(v);
    unsigned c;
    if (a < 1.25f)      c = (a < 0.25f) ? 0u : (a < 0.75f) ? 1u : 2u;
    else if (a < 2.5f)  c = (a < 1.75f) ? 3u : 4u;
    else                c = (a < 3.5f) ? 5u : (a < 5.0f) ? 6u : 7u;
    return c | (v < 0.f ? 8u : 0u);
}

// ---- 1) fused prep: norms + positives + fp4 rows + out zeroing ----
// One wave per pair i. Lane l owns elements 12l..12l+11 (3 contiguous float4).
__global__ __launch_bounds__(256) void prep_k(const float* __restrict__ h1,
                                              const float* __restrict__ h2,
                                              unsigned char* __restrict__ hn4,
                                              float* __restrict__ pos,
                                              float* __restrict__ out) {
    if (blockIdx.x == 0 && threadIdx.x == 0) out[0] = 0.f;  // before finalize (stream order)
    const int i = blockIdx.x * 4 + (threadIdx.x >> 6);
    const int lane = threadIdx.x & 63;
    const float4* a4 = (const float4*)(h1 + (size_t)i * D_SZ);
    const float4* b4 = (const float4*)(h2 + (size_t)i * D_SZ);
    float4 av[3], bv[3];
    float sa = 0.f, sb = 0.f, dt = 0.f;
#pragma unroll
    for (int j = 0; j < 3; ++j) {
        av[j] = a4[lane * 3 + j];
        bv[j] = b4[lane * 3 + j];
        sa += av[j].x * av[j].x + av[j].y * av[j].y + av[j].z * av[j].z + av[j].w * av[j].w;
        sb += bv[j].x * bv[j].x + bv[j].y * bv[j].y + bv[j].z * bv[j].z + bv[j].w * bv[j].w;
        dt += av[j].x * bv[j].x + av[j].y * bv[j].y + av[j].z * bv[j].z + av[j].w * bv[j].w;
    }
#pragma unroll
    for (int m = 1; m < 64; m <<= 1) {
        sa += __shfl_xor(sa, m, 64);
        sb += __shfl_xor(sb, m, 64);
        dt += __shfl_xor(dt, m, 64);
    }
    const float n1 = fmaxf(sqrtf(sa), 1e-8f), n2 = fmaxf(sqrtf(sb), 1e-8f);
    const float i1 = 1.0f / n1, i2 = 1.0f / n2;
    const float s1 = i1 * 16.0f, s2 = i2 * 16.0f;  // fp4 stores v*16, scale 2^-4
    unsigned short* d1 = (unsigned short*)(hn4 + (size_t)i * ROWB);
    unsigned short* d2 = (unsigned short*)(hn4 + (size_t)(i + B_SZ) * ROWB);
#pragma unroll
    for (int j = 0; j < 3; ++j) {
        float va[4] = {av[j].x, av[j].y, av[j].z, av[j].w};
        float vb[4] = {bv[j].x, bv[j].y, bv[j].z, bv[j].w};
        unsigned u1 = 0, u2 = 0;
#pragma unroll
        for (int e = 0; e < 4; ++e) {
            u1 |= fp4_enc(va[e] * s1) << (4 * e);
            u2 |= fp4_enc(vb[e] * s2) << (4 * e);
        }
        d1[lane * 3 + j] = (unsigned short)u1;
        d2[lane * 3 + j] = (unsigned short)u2;
    }
    if (lane == 0) {
        float p = dt * i1 * i2 * INV_T;
        pos[i] = p;
        pos[i + B_SZ] = p;
    }
}

// ---- 2) symmetric fused sim-GEMM (MX-fp4, 32x32x64) + exp partial sums ----
// 128x128 tile, 8 waves: wave w = m-strip (w&3)*32 x n-half (w>>2)*64,
// acc[2]=32 regs. B: LDS-staged (K=128 windows, 2 slabs of [128][32],
// double-buffered, all 8 waves stage 1 async16 each). A: direct global
// 16B fragment loads, one-window-ahead register prefetch. One
// __syncthreads per window.
#define BM 128
#define SLAB 4096            // 128 rows * 32 B
#define WINB 64              // fp4 bytes per row per window (K=128)
#define NWIN 6               // 768 / 128
#define BUFS 8192            // 2 slabs per buffer

__global__ __launch_bounds__(512) void gemm_reduce_k(const unsigned char* __restrict__ hn4,
                                                     float* __restrict__ part) {
    __shared__ __align__(16) unsigned char Bs[2 * BUFS];  // 16 KB
    // bijective XCD swizzle (2080 % 8 == 0): contiguous tri-indices per XCD
    const int b0 = blockIdx.x;
    const int b = (b0 & 7) * 260 + (b0 >> 3);
    // triangular index -> (ty, tx), ty <= tx
    int tx = (int)((sqrtf(8.0f * (float)b + 1.0f) - 1.0f) * 0.5f);
    while ((tx + 1) * (tx + 2) / 2 <= b) ++tx;
    while (tx * (tx + 1) / 2 > b) --tx;
    const int ty = b - tx * (tx + 1) / 2;
    const int rowBase = ty * BM;
    const int colBase = tx * BM;
    const bool diagBlk = (ty == tx);

    const int tid = threadIdx.x;
    const int wave = tid >> 6;   // 0..7
    const int lane = tid & 63;
    const int l32 = lane & 31;
    const int half = lane >> 5;
    const int ms = wave & 3;     // m-strip (32 rows)
    const int nh = wave >> 2;    // n-half (64 cols)

    f32x16 acc[2];
#pragma unroll
    for (int nt = 0; nt < 2; ++nt)
#pragma unroll
        for (int j = 0; j < 16; ++j) acc[nt][j] = 0.f;

    // B staging: wave w stages slab s=w&1, rows rb..rb+31 (rb=(w>>1)*32)
    // of the current window. Lane l -> row rb+(l>>1), slot l&1; global
    // chunk cg=(l&1)^((l>>3)&1) so slot holds chunk cg with the slab
    // swizzle slot = c ^ ((row>>2)&1) (verified R5+).
    const int sSt = wave & 1;
    const int rb = (wave >> 1) * 32;
    const int cg = (lane & 1) ^ ((lane >> 3) & 1);
    const unsigned char* gB =
        hn4 + (size_t)(colBase + rb + (lane >> 1)) * ROWB + sSt * 32 + cg * 16;
    unsigned char* lB = Bs + sSt * SLAB + rb * 32;  // + buf*BUFS

    // A fragment pointer (natural layout, 16B per slab per lane)
    const unsigned char* pa =
        hn4 + (size_t)(rowBase + ms * 32 + l32) * ROWB + half * 16;

    // B frag read offset (window/nt-invariant): slot p = half ^ ((l32>>2)&1).
    const int p = half ^ ((l32 >> 2) & 1);
    const int bO = (nh * 64 + l32) * 32 + p * 16;  // + nt*1024 + s*SLAB + buf*BUFS

    // prologue: stage B window 0 into buf 0; load A window 0 frags
    async16(gB, lB);
    i32x4 aCur[2];
    aCur[0] = *(const i32x4*)pa;
    aCur[1] = *(const i32x4*)(pa + 32);
    __syncthreads();

    for (int w = 0; w < NWIN; ++w) {
        const int buf = w & 1;
        i32x4 aNxt[2];
        if (w + 1 < NWIN) {  // issue next window's B staging + A frag loads
            const int o = (w + 1) * WINB;
            async16(gB + o, lB + (buf ^ 1) * BUFS);
            aNxt[0] = *(const i32x4*)(pa + o);
            aNxt[1] = *(const i32x4*)(pa + o + 32);
        }
        const unsigned char* Bb = Bs + buf * BUFS;
#pragma unroll
        for (int s = 0; s < 2; ++s) {
            i32x8 a = {aCur[s][0], aCur[s][1], aCur[s][2], aCur[s][3], 0, 0, 0, 0};
#pragma unroll
            for (int nt = 0; nt < 2; ++nt) {
                i32x4 bl = *(const i32x4*)(Bb + s * SLAB + bO + nt * 1024);
                i32x8 bf = {bl[0], bl[1], bl[2], bl[3], 0, 0, 0, 0};
                // fmtA=fmtB=4 (fp4); scales 2^-3 (0x7C) x 2^-4 (0x7B):
                // (16a*16b)*2^-7 = 2ab = sim/T folded into the MFMA.
                acc[nt] = __builtin_amdgcn_mfma_scale_f32_32x32x64_f8f6f4(
                    a, bf, acc[nt], 4, 4, 0, 0x7C7C7C7C, 0, 0x7B7B7B7B);
            }
        }
        __syncthreads();  // drains this window's prefetch (B DMA + A regs)
        aCur[0] = aNxt[0];
        aCur[1] = aNxt[1];
    }

    // epilogue: 32x32 C/D layout col=l32, row=(j&3)+8*(j>>2)+4*half
    // (shape-determined, verified R5..R10). Row-reduce on the VALU pipe
    // (DPP), per-wave partials into disjoint LDS slots, then PLAIN
    // exactly-once stores to part (no atomics).
    float* rowS = (float*)Bs;           // [nh=2][128]  (1 KB)
    float* colS = (float*)(Bs + 1024);  // [ms=4][128]  (2 KB)
    float rs[16];
#pragma unroll
    for (int j = 0; j < 16; ++j) rs[j] = 0.f;
    float csum[2] = {0.f, 0.f};
#pragma unroll
    for (int nt = 0; nt < 2; ++nt) {
        const int col = colBase + nh * 64 + nt * 32 + l32;
#pragma unroll
        for (int j = 0; j < 16; ++j) {
            const int row = rowBase + ms * 32 + (j & 3) + 8 * (j >> 2) + 4 * half;
            float e = __expf(acc[nt][j]);  // acc already = sim/T
            e = (diagBlk && row == col) ? 0.f : e;
            rs[j] += e;
            csum[nt] += e;
        }
    }
#pragma unroll
    for (int j = 0; j < 16; ++j) rs[j] = hsum32_dpp(rs[j]);  // lanes 31/63 valid
    if (l32 == 31) {  // lanes 31 and 63 (half 0/1) hold different rows
#pragma unroll
        for (int j = 0; j < 16; ++j)
            rowS[nh * 128 + ms * 32 + (j & 3) + 8 * (j >> 2) + 4 * half] = rs[j];
    }
#pragma unroll
    for (int nt = 0; nt < 2; ++nt) {
        float c = csum[nt] + __shfl_xor(csum[nt], 32, 64);
        if (half == 0) colS[ms * 128 + nh * 64 + nt * 32 + l32] = c;
    }
    __syncthreads();
    // part[a][b][r]: a<b row-part of block (a,b); a>b col-part of (b,a);
    // a==b diag row-part. Every slot written exactly once -> no zero/atomic.
    if (tid < 128) {
        part[((size_t)ty * 64 + tx) * 128 + tid] = rowS[tid] + rowS[128 + tid];
    } else if (tid < 256 && !diagBlk) {
        const int c = tid - 128;
        part[((size_t)tx * 64 + ty) * 128 + c] =
            colS[c] + colS[128 + c] + colS[256 + c] + colS[384 + c];
    }
}

// ---- 3) loss: 64 blocks x 128 thr; row r of tile t: sum 64 partials,
// log - pos, block-reduce, 64 atomicAdds on out[0] (zeroed by prep). ----
__global__ __launch_bounds__(128) void finalize_k(const float* __restrict__ part,
                                                  const float* __restrict__ pos,
                                                  float* __restrict__ out) {
    __shared__ float red[2];
    const int t = blockIdx.x;
    const int r = threadIdx.x;
    const float* p = part + (size_t)t * 64 * 128 + r;
    float s = 0.f;
#pragma unroll 16
    for (int u = 0; u < 64; ++u) s += p[u * 128];
    const int i = t * 128 + r;
    float v = __logf(s) - pos[i];
#pragma unroll
    for (int m = 1; m < 64; m <<= 1) v += __shfl_xor(v, m, 64);
    if ((r & 63) == 0) red[r >> 6] = v;
    __syncthreads();
    if (r == 0) atomicAdd(out, (red[0] + red[1]) * (1.0f / (float)N_SZ));
}

extern "C" void kernel_launch(void* const* d_in, const int* in_sizes, int n_in,
                              void* d_out, int out_size, void* d_ws, size_t ws_size,
                              hipStream_t stream) {
    const float* h1 = (const float*)d_in[0];
    const float* h2 = (const float*)d_in[1];
    float* out = (float*)d_out;

    char* ws = (char*)d_ws;
    unsigned char* hn4 = (unsigned char*)ws;                     // N*384 = 3,145,728 B
    float* pos  = (float*)(ws + (size_t)N_SZ * ROWB);            // 32 KB
    float* part = (float*)(ws + (size_t)N_SZ * ROWB + 32768);    // 64*64*128*4 = 2 MB

    prep_k<<<B_SZ / 4, 256, 0, stream>>>(h1, h2, hn4, pos, out);
    const int nTiles = N_SZ / BM;                    // 64
    const int nBlocks = nTiles * (nTiles + 1) / 2;   // 2080
    gemm_reduce_k<<<nBlocks, 512, 0, stream>>>(hn4, part);
    finalize_k<<<64, 128, 0, stream>>>(part, pos, out);
}

// Round 12
// 99.686 us; speedup vs baseline: 1.5046x; 1.1288x over previous
//
#include <hip/hip_runtime.h>
#include <hip/hip_bf16.h>

// InfoNCE loss, B=4096 D=768 N=8192, T=0.5, fp32 in, fp32 scalar out.
// R23: R19 base (best, 103.0us: triple-probe-validated structure: LDS-
// staged both operands, 8 waves x 32x64 wave-tile, DPP epilogue, no-atomic
// exactly-once part stores) + barrier-event reduction: K windows widened
// 128->192 (3 slabs of 32B/row), NWIN 6->4, barrier events/block 7->5.
// Totals unchanged: 36 ds_read + 24 MFMA per wave, same staged bytes,
// 48 KB LDS (=R19) -> same 3 blocks/CU, VGPR ~60 << 128 cap. Schedule =
// R16's proven double-buffer (stage next window BEFORE compute, ONE
// __syncthreads per window; R16==R17 proved drain style is neutral).
// Probes mapped: bigger wave-tile x (occupancy), no-LDS x (latency),
// A-off-LDS x (latency), counted vmcnt ~0, atomics ~0, DPP +7us.

#define B_SZ 4096
#define D_SZ 768
#define N_SZ 8192
#define ROWB 384  // fp4 bytes per row (768 * 0.5)
constexpr float INV_T = 2.0f;  // 1/temperature

typedef float f32x16 __attribute__((ext_vector_type(16)));
typedef int i32x8 __attribute__((ext_vector_type(8)));
typedef int i32x4 __attribute__((ext_vector_type(4)));
typedef __attribute__((address_space(1))) const unsigned int gu32;
typedef __attribute__((address_space(3))) unsigned int lu32;

__device__ inline void async16(const void* g, void* l) {
    // per-lane global addr, wave-uniform LDS base; lane i lands at base + i*16.
    __builtin_amdgcn_global_load_lds((gu32*)g, (lu32*)l, 16, 0, 0);
}

// DPP half-wave (32-lane) sum on the VALU pipe: row_shr 1/2/4/8 then
// row_bcast:15 (row_mask 0xa) -> lanes 31 and 63 hold the two half sums.
// bound_ctrl=1: shifted-in lanes contribute 0.
__device__ inline float hsum32_dpp(float x) {
    float s = x, t;
    t = __int_as_float(__builtin_amdgcn_update_dpp(0, __float_as_int(s), 0x111, 0xf, 0xf, true)); s += t;
    t = __int_as_float(__builtin_amdgcn_update_dpp(0, __float_as_int(s), 0x112, 0xf, 0xf, true)); s += t;
    t = __int_as_float(__builtin_amdgcn_update_dpp(0, __float_as_int(s), 0x114, 0xf, 0xf, true)); s += t;
    t = __int_as_float(__builtin_amdgcn_update_dpp(0, __float_as_int(s), 0x118, 0xf, 0xf, true)); s += t;
    t = __int_as_float(__builtin_amdgcn_update_dpp(0, __float_as_int(s), 0x142, 0xa, 0xf, true)); s += t;
    return s;  // valid in lanes 31 and 63
}

// e2m1 encode of v (pre-scaled); levels 0,.5,1,1.5,2,3,4,6; round-to-nearest.
__device__ inline unsigned fp4_enc(float v) {
    float a = fabsf(v);
    unsigned c;
    if (a < 1.25f)      c = (a < 0.25f) ? 0u : (a < 0.75f) ? 1u : 2u;
    else if (a < 2.5f)  c = (a < 1.75f) ? 3u : 4u;
    else                c = (a < 3.5f) ? 5u : (a < 5.0f) ? 6u : 7u;
    return c | (v < 0.f ? 8u : 0u);
}

// ---- 1) fused prep: norms + positives + fp4 rows + out zeroing ----
// One wave per pair i. Lane l owns elements 12l..12l+11 (3 contiguous float4).
__global__ __launch_bounds__(256) void prep_k(const float* __restrict__ h1,
                                              const float* __restrict__ h2,
                                              unsigned char* __restrict__ hn4,
                                              float* __restrict__ pos,
                                              float* __restrict__ out) {
    if (blockIdx.x == 0 && threadIdx.x == 0) out[0] = 0.f;  // before finalize (stream order)
    const int i = blockIdx.x * 4 + (threadIdx.x >> 6);
    const int lane = threadIdx.x & 63;
    const float4* a4 = (const float4*)(h1 + (size_t)i * D_SZ);
    const float4* b4 = (const float4*)(h2 + (size_t)i * D_SZ);
    float4 av[3], bv[3];
    float sa = 0.f, sb = 0.f, dt = 0.f;
#pragma unroll
    for (int j = 0; j < 3; ++j) {
        av[j] = a4[lane * 3 + j];
        bv[j] = b4[lane * 3 + j];
        sa += av[j].x * av[j].x + av[j].y * av[j].y + av[j].z * av[j].z + av[j].w * av[j].w;
        sb += bv[j].x * bv[j].x + bv[j].y * bv[j].y + bv[j].z * bv[j].z + bv[j].w * bv[j].w;
        dt += av[j].x * bv[j].x + av[j].y * bv[j].y + av[j].z * bv[j].z + av[j].w * bv[j].w;
    }
#pragma unroll
    for (int m = 1; m < 64; m <<= 1) {
        sa += __shfl_xor(sa, m, 64);
        sb += __shfl_xor(sb, m, 64);
        dt += __shfl_xor(dt, m, 64);
    }
    const float n1 = fmaxf(sqrtf(sa), 1e-8f), n2 = fmaxf(sqrtf(sb), 1e-8f);
    const float i1 = 1.0f / n1, i2 = 1.0f / n2;
    const float s1 = i1 * 16.0f, s2 = i2 * 16.0f;  // fp4 stores v*16, scale 2^-4
    unsigned short* d1 = (unsigned short*)(hn4 + (size_t)i * ROWB);
    unsigned short* d2 = (unsigned short*)(hn4 + (size_t)(i + B_SZ) * ROWB);
#pragma unroll
    for (int j = 0; j < 3; ++j) {
        float va[4] = {av[j].x, av[j].y, av[j].z, av[j].w};
        float vb[4] = {bv[j].x, bv[j].y, bv[j].z, bv[j].w};
        unsigned u1 = 0, u2 = 0;
#pragma unroll
        for (int e = 0; e < 4; ++e) {
            u1 |= fp4_enc(va[e] * s1) << (4 * e);
            u2 |= fp4_enc(vb[e] * s2) << (4 * e);
        }
        d1[lane * 3 + j] = (unsigned short)u1;
        d2[lane * 3 + j] = (unsigned short)u2;
    }
    if (lane == 0) {
        float p = dt * i1 * i2 * INV_T;
        pos[i] = p;
        pos[i + B_SZ] = p;
    }
}

// ---- 2) symmetric fused sim-GEMM (MX-fp4, 32x32x64) + exp partial sums ----
// 128x128 tile, 8 waves: wave w = m-strip (w&3)*32 x n-half (w>>2)*64,
// acc[2]=32 regs. K windows of 192 (3 slabs of 32 B/row), double-buffered;
// per window: issue next window's 3 global_load_lds per wave BEFORE
// compute, ds_read+MFMA current, ONE __syncthreads (drains prefetch).
// Slab swizzle: 16B chunk c of row r at slot c^((r>>2)&1) (verified R5+).
#define BM 128
#define SLAB 4096            // 128 rows * 32 B
#define SPW 3                // slabs per window (K=192)
#define WINB 96              // fp4 bytes per row per window
#define NWIN 4               // 768 / 192
#define BUFS 12288           // 3 slabs per buffer

__global__ __launch_bounds__(512) void gemm_reduce_k(const unsigned char* __restrict__ hn4,
                                                     float* __restrict__ part) {
    __shared__ __align__(16) unsigned char As[2 * BUFS];  // 24 KB
    __shared__ __align__(16) unsigned char Bs[2 * BUFS];  // 24 KB
    // bijective XCD swizzle (2080 % 8 == 0): contiguous tri-indices per XCD
    const int b0 = blockIdx.x;
    const int b = (b0 & 7) * 260 + (b0 >> 3);
    // triangular index -> (ty, tx), ty <= tx
    int tx = (int)((sqrtf(8.0f * (float)b + 1.0f) - 1.0f) * 0.5f);
    while ((tx + 1) * (tx + 2) / 2 <= b) ++tx;
    while (tx * (tx + 1) / 2 > b) --tx;
    const int ty = b - tx * (tx + 1) / 2;
    const int rowBase = ty * BM;
    const int colBase = tx * BM;
    const bool diagBlk = (ty == tx);

    const int tid = threadIdx.x;
    const int wave = tid >> 6;   // 0..7
    const int lane = tid & 63;
    const int l32 = lane & 31;
    const int half = lane >> 5;
    const int ms = wave & 3;     // m-strip (32 rows)
    const int nh = wave >> 2;    // n-half (64 cols)

    f32x16 acc[2];
#pragma unroll
    for (int nt = 0; nt < 2; ++nt)
#pragma unroll
        for (int j = 0; j < 16; ++j) acc[nt][j] = 0.f;

    // staging: waves 0-3 stage A strip ms, waves 4-7 stage B strip ms.
    // Lane l -> row ms*32 + (l>>1); fetches global 16B chunk (l&1)^((l>>3)&1)
    // so after the linear lane->slot DMA, logical chunk c of row r sits at
    // slot c^((r>>2)&1). Three async16 per window (slabs s=0..2).
    const bool stB = wave >= 4;
    const int cg = (lane & 1) ^ ((lane >> 3) & 1);
    const unsigned char* gsrc =
        hn4 + (size_t)((stB ? colBase : rowBase) + ms * 32 + (lane >> 1)) * ROWB + cg * 16;
    unsigned char* ldst = (stB ? Bs : As) + ms * 1024;  // + s*SLAB + buf*BUFS

    // frag read offsets (window-invariant): slot p = half ^ ((l32>>2)&1).
    const int p = half ^ ((l32 >> 2) & 1);
    const int aOff = (ms * 32 + l32) * 32 + p * 16;
    const int bOff = (nh * 64 + l32) * 32 + p * 16;  // + nt*1024

    // prologue: stage window 0 into buf 0
#pragma unroll
    for (int s = 0; s < SPW; ++s)
        async16(gsrc + s * 32, ldst + s * SLAB);
    __syncthreads();

    for (int w = 0; w < NWIN; ++w) {
        const int buf = w & 1;
        if (w + 1 < NWIN) {  // issue next window's loads BEFORE compute
            const unsigned char* g0 = gsrc + (w + 1) * WINB;
            unsigned char* l0 = ldst + (buf ^ 1) * BUFS;
#pragma unroll
            for (int s = 0; s < SPW; ++s)
                async16(g0 + s * 32, l0 + s * SLAB);
        }
        const unsigned char* Ab = As + buf * BUFS;
        const unsigned char* Bb = Bs + buf * BUFS;
#pragma unroll
        for (int s = 0; s < SPW; ++s) {
            i32x4 al = *(const i32x4*)(Ab + s * SLAB + aOff);
            i32x8 a = {al[0], al[1], al[2], al[3], 0, 0, 0, 0};
#pragma unroll
            for (int nt = 0; nt < 2; ++nt) {
                i32x4 bl = *(const i32x4*)(Bb + s * SLAB + bOff + nt * 1024);
                i32x8 bf = {bl[0], bl[1], bl[2], bl[3], 0, 0, 0, 0};
                // fmtA=fmtB=4 (fp4); scales 2^-3 (0x7C) x 2^-4 (0x7B):
                // (16a*16b)*2^-7 = 2ab = sim/T folded into the MFMA.
                acc[nt] = __builtin_amdgcn_mfma_scale_f32_32x32x64_f8f6f4(
                    a, bf, acc[nt], 4, 4, 0, 0x7C7C7C7C, 0, 0x7B7B7B7B);
            }
        }
        __syncthreads();  // drains this window's prefetch too (vmcnt 0)
    }

    // epilogue: 32x32 C/D layout col=l32, row=(j&3)+8*(j>>2)+4*half
    // (shape-determined, verified R5..R10). Row-reduce on the VALU pipe
    // (DPP), per-wave partials into disjoint LDS slots, then PLAIN
    // exactly-once stores to part (no atomics).
    float* rowS = (float*)As;           // [nh=2][128]  (1 KB)
    float* colS = (float*)(As + 1024);  // [ms=4][128]  (2 KB)
    float rs[16];
#pragma unroll
    for (int j = 0; j < 16; ++j) rs[j] = 0.f;
    float csum[2] = {0.f, 0.f};
#pragma unroll
    for (int nt = 0; nt < 2; ++nt) {
        const int col = colBase + nh * 64 + nt * 32 + l32;
#pragma unroll
        for (int j = 0; j < 16; ++j) {
            const int row = rowBase + ms * 32 + (j & 3) + 8 * (j >> 2) + 4 * half;
            float e = __expf(acc[nt][j]);  // acc already = sim/T
            e = (diagBlk && row == col) ? 0.f : e;
            rs[j] += e;
            csum[nt] += e;
        }
    }
#pragma unroll
    for (int j = 0; j < 16; ++j) rs[j] = hsum32_dpp(rs[j]);  // lanes 31/63 valid
    if (l32 == 31) {  // lanes 31 and 63 (half 0/1) hold different rows
#pragma unroll
        for (int j = 0; j < 16; ++j)
            rowS[nh * 128 + ms * 32 + (j & 3) + 8 * (j >> 2) + 4 * half] = rs[j];
    }
#pragma unroll
    for (int nt = 0; nt < 2; ++nt) {
        float c = csum[nt] + __shfl_xor(csum[nt], 32, 64);
        if (half == 0) colS[ms * 128 + nh * 64 + nt * 32 + l32] = c;
    }
    __syncthreads();
    // part[a][b][r]: a<b row-part of block (a,b); a>b col-part of (b,a);
    // a==b diag row-part. Every slot written exactly once -> no zero/atomic.
    if (tid < 128) {
        part[((size_t)ty * 64 + tx) * 128 + tid] = rowS[tid] + rowS[128 + tid];
    } else if (tid < 256 && !diagBlk) {
        const int c = tid - 128;
        part[((size_t)tx * 64 + ty) * 128 + c] =
            colS[c] + colS[128 + c] + colS[256 + c] + colS[384 + c];
    }
}

// ---- 3) loss: 64 blocks x 128 thr; row r of tile t: sum 64 partials,
// log - pos, block-reduce, 64 atomicAdds on out[0] (zeroed by prep). ----
__global__ __launch_bounds__(128) void finalize_k(const float* __restrict__ part,
                                                  const float* __restrict__ pos,
                                                  float* __restrict__ out) {
    __shared__ float red[2];
    const int t = blockIdx.x;
    const int r = threadIdx.x;
    const float* p = part + (size_t)t * 64 * 128 + r;
    float s = 0.f;
#pragma unroll 16
    for (int u = 0; u < 64; ++u) s += p[u * 128];
    const int i = t * 128 + r;
    float v = __logf(s) - pos[i];
#pragma unroll
    for (int m = 1; m < 64; m <<= 1) v += __shfl_xor(v, m, 64);
    if ((r & 63) == 0) red[r >> 6] = v;
    __syncthreads();
    if (r == 0) atomicAdd(out, (red[0] + red[1]) * (1.0f / (float)N_SZ));
}

extern "C" void kernel_launch(void* const* d_in, const int* in_sizes, int n_in,
                              void* d_out, int out_size, void* d_ws, size_t ws_size,
                              hipStream_t stream) {
    const float* h1 = (const float*)d_in[0];
    const float* h2 = (const float*)d_in[1];
    float* out = (float*)d_out;

    char* ws = (char*)d_ws;
    unsigned char* hn4 = (unsigned char*)ws;                     // N*384 = 3,145,728 B
    float* pos  = (float*)(ws + (size_t)N_SZ * ROWB);            // 32 KB
    float* part = (float*)(ws + (size_t)N_SZ * ROWB + 32768);    // 64*64*128*4 = 2 MB

    prep_k<<<B_SZ / 4, 256, 0, stream>>>(h1, h2, hn4, pos, out);
    const int nTiles = N_SZ / BM;                    // 64
    const int nBlocks = nTiles * (nTiles + 1) / 2;   // 2080
    gemm_reduce_k<<<nBlocks, 512, 0, stream>>>(hn4, part);
    finalize_k<<<64, 128, 0, stream>>>(part, pos, out);
}